// Round 3
// baseline (2136.015 us; speedup 1.0000x reference)
//
#include <hip/hip_runtime.h>
#include <math.h>

#define BB 8
#define LL 2048
#define DD 256

typedef float  f4_t __attribute__((ext_vector_type(4)));
typedef short  s8_t __attribute__((ext_vector_type(8)));

union S8U { s8_t v; unsigned u[4]; };

__device__ __forceinline__ unsigned bitsf(float x){ union{float f; unsigned u;} c; c.f=x; return c.u; }
__device__ __forceinline__ float fbits(unsigned u){ union{float f; unsigned u;} c; c.u=u; return c.f; }
// pack two fp32 -> two bf16 (truncate), elem0 in low half
__device__ __forceinline__ unsigned pkhi(float a, float b){ return (bitsf(a)>>16) | (bitsf(b)&0xffff0000u); }
// pack two fp32 -> two bf16 (round-nearest-ish)
__device__ __forceinline__ unsigned pkrn(float a, float b){
    unsigned ua = bitsf(a) + 0x8000u, ub = bitsf(b) + 0x8000u;
    return (ua>>16) | (ub&0xffff0000u);
}

// sigma: row e (0..31) of the key tile -> Vperm slot; makes P's MFMA C/D layout
// directly usable as the PV A-operand (slot k=8q+4a+b holds j=16a+4q+b).
__device__ __forceinline__ int vslot(int e){ return ((e>>2)&3)*8 + ((e>>4)<<2) + (e&3); }

// ---------------- MFMA flash attention — R3: 8-wave blocks + 4-way K-split ----------------
// R2 proved the 16-q-rows-per-wave shape compiles to 124 VGPR -> the HW can host
// 4 waves/SIMD (vgpr step at 128, m69). R1's 4-way split failed only because the
// old 32-row shape (~380 unified regs) pinned residency at 1 wave/SIMD. Now:
// grid 512 (8 bb x 16 qb x 4 K-quarters) x 512 thr, __launch_bounds__(512,4)
// -> 2 blocks/CU, 16 waves/CU. LDS 51.2KB x 2 = 102KB <= 160KB.
__global__ __launch_bounds__(512,4)
void attn_kernel(const float* __restrict__ c1, const float* __restrict__ c2,
                 const unsigned char* __restrict__ cmask,
                 float* __restrict__ o0, float* __restrict__ o1,
                 float* __restrict__ o2, float* __restrict__ o3,
                 float* __restrict__ mlp,
                 int klen, int split)
{
    __shared__ short Khi[32*264];
    __shared__ short Klo[32*264];
    __shared__ short Vp [256*34];

    const int tid  = threadIdx.x;
    const int lane = tid & 63;
    const int w    = tid >> 6;          // 0..7
    const int il   = lane & 15;
    const int quad = lane >> 4;
    const int col  = tid & 255;         // staging column (d-index)
    const int hr   = (tid >> 8) * 16;   // staging row base (0 or 16)

    const int blk  = blockIdx.x;
    const int bb   = blk & 7;
    const int qb   = (blk >> 3) & 15;
    const int half = split ? (blk >> 7) : 0;   // 0..3 when grid=512
    const int kb   = half * klen;

    float* ob = (half == 0) ? o0 : (half == 1) ? o1 : (half == 2) ? o2 : o3;

    const float* c1b = c1 + (size_t)bb * LL * DD;
    const float* c2b = c2 + (size_t)bb * LL * DD;
    const unsigned char* mb = cmask + (size_t)bb * LL;

    const int q0w = qb*128 + w*16;      // 16 q-rows per wave

    // Q fragments (hi/lo bf16 split), 1 n-tile per wave
    s8_t qh[8], ql[8];
    {
        const float* qp = c2b + (size_t)(q0w + il)*DD + quad*8;
#pragma unroll
        for (int kd = 0; kd < 8; ++kd) {
            float4 x0 = *(const float4*)(qp + kd*32);
            float4 x1 = *(const float4*)(qp + kd*32 + 4);
            float e[8] = {x0.x,x0.y,x0.z,x0.w,x1.x,x1.y,x1.z,x1.w};
            S8U h, l;
#pragma unroll
            for (int p2 = 0; p2 < 4; ++p2) {
                float a = e[2*p2], b = e[2*p2+1];
                h.u[p2] = pkhi(a, b);
                float alo = a - fbits(bitsf(a)&0xffff0000u);
                float blo = b - fbits(bitsf(b)&0xffff0000u);
                l.u[p2] = pkhi(alo, blo);
            }
            qh[kd] = h.v; ql[kd] = l.v;
        }
    }

    f4_t o[16];
#pragma unroll
    for (int n = 0; n < 16; ++n) o[n] = (f4_t)0.0f;
    float m_s = -INFINITY;
    float l_s = 0.f;

    const int NT = klen >> 5;
    float g[16];

    // initial K/V tile stage: each thread loads 16 rows of its column
#pragma unroll
    for (int e = 0; e < 16; ++e) g[e] = c1b[(size_t)(kb + hr + e)*DD + col];
#pragma unroll
    for (int e = 0; e < 16; ++e) {
        unsigned ub = bitsf(g[e]);
        Khi[(hr + e)*264 + col] = (short)(ub >> 16);
        float lo = g[e] - fbits(ub & 0xffff0000u);
        Klo[(hr + e)*264 + col] = (short)(bitsf(lo) >> 16);
    }
#pragma unroll
    for (int e = 0; e < 16; e += 2)
        ((unsigned*)Vp)[col*17 + (vslot(hr + e)>>1)] = pkrn(g[e], g[e+1]);
    __syncthreads();

    for (int kt = 0; kt < NT; ++kt) {
        const int k0 = kt << 5;
        if (kt + 1 < NT) {
#pragma unroll
            for (int e = 0; e < 16; ++e)
                g[e] = c1b[(size_t)(kb + k0 + 32 + hr + e)*DD + col];
        }

        f4_t acc[2];
        acc[0] = (f4_t)0.0f;
        acc[1] = (f4_t)0.0f;

#pragma unroll
        for (int kd = 0; kd < 8; ++kd) {
            s8_t ah0 = *(const s8_t*)&Khi[(il     )*264 + kd*32 + quad*8];
            s8_t ah1 = *(const s8_t*)&Khi[(16 + il)*264 + kd*32 + quad*8];
            s8_t al0 = *(const s8_t*)&Klo[(il     )*264 + kd*32 + quad*8];
            s8_t al1 = *(const s8_t*)&Klo[(16 + il)*264 + kd*32 + quad*8];
            acc[0] = __builtin_amdgcn_mfma_f32_16x16x32_bf16(ah0, qh[kd], acc[0], 0,0,0);
            acc[1] = __builtin_amdgcn_mfma_f32_16x16x32_bf16(ah1, qh[kd], acc[1], 0,0,0);
            acc[0] = __builtin_amdgcn_mfma_f32_16x16x32_bf16(al0, qh[kd], acc[0], 0,0,0);
            acc[1] = __builtin_amdgcn_mfma_f32_16x16x32_bf16(al1, qh[kd], acc[1], 0,0,0);
            acc[0] = __builtin_amdgcn_mfma_f32_16x16x32_bf16(ah0, ql[kd], acc[0], 0,0,0);
            acc[1] = __builtin_amdgcn_mfma_f32_16x16x32_bf16(ah1, ql[kd], acc[1], 0,0,0);
        }

        unsigned mu[2];
#pragma unroll
        for (int mj = 0; mj < 2; ++mj)
            mu[mj] = *(const unsigned*)(mb + kb + k0 + 16*mj + 4*quad);

        // online softmax for this wave's 16 q-rows (row = il after quad-reduce)
        const int ig = q0w + il;
        float mn = m_s;
        f4_t p[2];
#pragma unroll
        for (int mj = 0; mj < 2; ++mj) {
#pragma unroll
            for (int b = 0; b < 4; ++b) {
                int jg = kb + k0 + 16*mj + 4*quad + b;
                float s = acc[mj][b];
                bool dead = (((mu[mj] >> (8*b)) & 0xff) != 0) || (jg == ig);
                s = dead ? -INFINITY : s;
                p[mj][b] = s;
                mn = fmaxf(mn, s);
            }
        }
        mn = fmaxf(mn, __shfl_xor(mn, 16, 64));
        mn = fmaxf(mn, __shfl_xor(mn, 32, 64));
        float al = __expf(m_s - mn);
        float rs = 0.f;
#pragma unroll
        for (int mj = 0; mj < 2; ++mj) {
#pragma unroll
            for (int b = 0; b < 4; ++b) {
                float pe = __expf(p[mj][b] - mn);
                p[mj][b] = pe;
                rs += pe;
            }
        }
        rs += __shfl_xor(rs, 16, 64);
        rs += __shfl_xor(rs, 32, 64);
        l_s = l_s*al + rs;
        m_s = mn;

        // rescale running O
        {
            float am[4];
#pragma unroll
            for (int b = 0; b < 4; ++b) am[b] = __shfl(al, 4*quad + b, 64);
#pragma unroll
            for (int n = 0; n < 16; ++n) {
#pragma unroll
                for (int b = 0; b < 4; ++b) o[n][b] *= am[b];
            }
        }

        // pack P -> bf16 A-fragment
        s8_t ap;
        {
            S8U a;
            a.u[0] = pkrn(p[0][0], p[0][1]);
            a.u[1] = pkrn(p[0][2], p[0][3]);
            a.u[2] = pkrn(p[1][0], p[1][1]);
            a.u[3] = pkrn(p[1][2], p[1][3]);
            ap = a.v;
        }
#pragma unroll
        for (int n = 0; n < 16; ++n) {
            S8U bv;
#pragma unroll
            for (int dd = 0; dd < 4; ++dd)
                bv.u[dd] = ((const unsigned*)Vp)[(16*n + il)*17 + quad*4 + dd];
            o[n] = __builtin_amdgcn_mfma_f32_16x16x32_bf16(ap, bv.v, o[n], 0,0,0);
        }

        __syncthreads();
        if (kt + 1 < NT) {
#pragma unroll
            for (int e = 0; e < 16; ++e) {
                unsigned ub = bitsf(g[e]);
                Khi[(hr + e)*264 + col] = (short)(ub >> 16);
                float lo = g[e] - fbits(ub & 0xffff0000u);
                Klo[(hr + e)*264 + col] = (short)(bitsf(lo) >> 16);
            }
#pragma unroll
            for (int e = 0; e < 16; e += 2)
                ((unsigned*)Vp)[col*17 + (vslot(hr + e)>>1)] = pkrn(g[e], g[e+1]);
        }
        __syncthreads();
    }

    const int rbq = bb*LL + q0w;
    if (split) {
        const int rbase = rbq + 4*quad;
#pragma unroll
        for (int n = 0; n < 16; ++n) {
            const int d = 16*n + il;
#pragma unroll
            for (int b = 0; b < 4; ++b)
                ob[(size_t)(rbase + b)*DD + d] = o[n][b];
        }
        if (lane < 16) {
            int r = rbq + lane;
            *(float2*)(&mlp[((size_t)half*16384 + r)*2]) = make_float2(m_s, l_s);
        }
    } else {
        float invl[4];
#pragma unroll
        for (int b = 0; b < 4; ++b) invl[b] = 1.0f / __shfl(l_s, 4*quad + b, 64);
        const int rbase = rbq + 4*quad;
#pragma unroll
        for (int n = 0; n < 16; ++n) {
            const int d = 16*n + il;
#pragma unroll
            for (int b = 0; b < 4; ++b)
                ob[(size_t)(rbase + b)*DD + d] = o[n][b] * invl[b];
        }
    }
}

// ---------------- split-K flash combine (ns-way, uniform branch) ----------------
// partial0 may alias aug (each thread reads its own element then writes the
// same element -> no hazard).
__global__ __launch_bounds__(256)
void combine_kernel(const float* __restrict__ o0, const float* __restrict__ o1,
                    const float* __restrict__ o2, const float* __restrict__ o3,
                    const float* __restrict__ mlp, float* __restrict__ aug, int ns)
{
    int t = blockIdx.x*256 + threadIdx.x;
    int r = t >> 6, c = (t & 63) << 2;

    float m[4], l[4];
#pragma unroll
    for (int h = 0; h < 4; ++h) {
        if (h < ns) {
            m[h] = mlp[((size_t)h*16384 + r)*2];
            l[h] = mlp[((size_t)h*16384 + r)*2 + 1];
        } else { m[h] = -INFINITY; l[h] = 0.f; }
    }
    float M = fmaxf(fmaxf(m[0], m[1]), fmaxf(m[2], m[3]));

    f4_t res = (f4_t)0.0f;
    float den = 0.f;
#pragma unroll
    for (int h = 0; h < 4; ++h) {
        if (h < ns) {
            float a = __expf(m[h] - M);
            den += a * l[h];
            const float* oh = (h == 0) ? o0 : (h == 1) ? o1 : (h == 2) ? o2 : o3;
            f4_t x = *(const f4_t*)(oh + (size_t)r*DD + c);
            res += x * a;
        }
    }
    res *= (1.0f / den);
    *(f4_t*)(aug + (size_t)r*DD + c) = res;
}

// ---------------- prep (unchanged) ----------------
__global__ __launch_bounds__(256)
void prep_kernel(const float* __restrict__ Wf, const float* __restrict__ Wg,
                 unsigned* __restrict__ Whi, unsigned* __restrict__ Wlo,
                 float* __restrict__ gw)
{
    if (blockIdx.x == 384) {
#pragma unroll
        for (int i = 0; i < 3; ++i) {
            int kl = threadIdx.x;
            float v = (i == 0) ? (Wg[kl] + Wg[768 + kl])
                    : (i == 1) ? (Wg[256 + kl] - Wg[768 + kl])
                               :  Wg[512 + kl];
            gw[i*256 + kl] = v;
        }
        return;
    }
    int t    = blockIdx.x*256 + threadIdx.x;    // [0, 98304)
    int p    = t & 3;
    int lane = (t >> 2) & 63;
    int nt   = (t >> 8) & 15;
    int g2   = t >> 12;                          // kc*3 + seg, [0,24)
    int seg  = g2 % 3;
    int kc   = g2 / 3;
    int kl   = kc*32 + (lane >> 4)*8 + 2*p;
    int n    = nt*16 + (lane & 15);
    float v0, v1;
    if (seg == 0) {
        v0 = Wf[(size_t)kl*DD + n]       + Wf[(size_t)(768 + kl)*DD + n];
        v1 = Wf[(size_t)(kl + 1)*DD + n] + Wf[(size_t)(769 + kl)*DD + n];
    } else if (seg == 1) {
        v0 = Wf[(size_t)(256 + kl)*DD + n] - Wf[(size_t)(768 + kl)*DD + n];
        v1 = Wf[(size_t)(257 + kl)*DD + n] - Wf[(size_t)(769 + kl)*DD + n];
    } else {
        v0 = Wf[(size_t)(512 + kl)*DD + n];
        v1 = Wf[(size_t)(513 + kl)*DD + n];
    }
    Whi[t] = pkhi(v0, v1);
    float l0 = v0 - fbits(bitsf(v0) & 0xffff0000u);
    float l1 = v1 - fbits(bitsf(v1) & 0xffff0000u);
    Wlo[t] = pkrn(l0, l1);
}

// ---------------- MFMA fusion (unchanged) ----------------
__global__ __launch_bounds__(256,1)
void fusion_mfma(const float* __restrict__ c2, const float* __restrict__ aug,
                 const unsigned* __restrict__ Whi, const unsigned* __restrict__ Wlo,
                 const float* __restrict__ gw, const float* __restrict__ bg,
                 const float* __restrict__ bf, float* __restrict__ out)
{
    __shared__ float gwL[768];
    __shared__ float gv[64];

    const int tid  = threadIdx.x;
    const int lane = tid & 63;
    const int w    = tid >> 6;
    const int il   = lane & 15;
    const int quad = lane >> 4;
    const size_t row0 = (size_t)blockIdx.x * 64;

    const float* c2b  = c2 + row0*DD;
    const float* augb = aug + row0*DD;

    for (int i = tid; i < 768; i += 256) gwL[i] = gw[i];
    __syncthreads();

    f4_t acc[4][4];
#pragma unroll
    for (int mt = 0; mt < 4; ++mt)
#pragma unroll
        for (int nt = 0; nt < 4; ++nt) acc[mt][nt] = (f4_t)0.0f;
    float gp[4] = {0.f, 0.f, 0.f, 0.f};

    for (int kc = 0; kc < 8; ++kc) {
        s8_t za[4], zb[4], zc[4];
        const int c0 = kc*32 + quad*8;
#pragma unroll
        for (int mt = 0; mt < 4; ++mt) {
            const float* pr = c2b  + (size_t)(16*mt + il)*DD + c0;
            const float* pu = augb + (size_t)(16*mt + il)*DD + c0;
            float4 a0 = *(const float4*)pr, a1 = *(const float4*)(pr + 4);
            float4 u0 = *(const float4*)pu, u1 = *(const float4*)(pu + 4);
            float ea[8] = {a0.x,a0.y,a0.z,a0.w,a1.x,a1.y,a1.z,a1.w};
            float eu[8] = {u0.x,u0.y,u0.z,u0.w,u1.x,u1.y,u1.z,u1.w};
#pragma unroll
            for (int j = 0; j < 8; ++j)
                gp[mt] += ea[j]*gwL[c0+j] + eu[j]*gwL[256+c0+j] + (ea[j]*eu[j])*gwL[512+c0+j];
            S8U A, U, Pd;
#pragma unroll
            for (int p = 0; p < 4; ++p) {
                A.u[p]  = pkrn(ea[2*p], ea[2*p+1]);
                U.u[p]  = pkrn(eu[2*p], eu[2*p+1]);
                Pd.u[p] = pkrn(ea[2*p]*eu[2*p], ea[2*p+1]*eu[2*p+1]);
            }
            za[mt] = A.v; zb[mt] = U.v; zc[mt] = Pd.v;
        }
#pragma unroll
        for (int nt = 0; nt < 4; ++nt) {
            const int ntg = w*4 + nt;
            const size_t f0 = ((size_t)((kc*3 + 0)*16 + ntg)*64 + lane)*4;
            const size_t f1 = ((size_t)((kc*3 + 1)*16 + ntg)*64 + lane)*4;
            const size_t f2 = ((size_t)((kc*3 + 2)*16 + ntg)*64 + lane)*4;
            s8_t w0h = *(const s8_t*)(Whi + f0), w0l = *(const s8_t*)(Wlo + f0);
            s8_t w1h = *(const s8_t*)(Whi + f1), w1l = *(const s8_t*)(Wlo + f1);
            s8_t w2h = *(const s8_t*)(Whi + f2), w2l = *(const s8_t*)(Wlo + f2);
#pragma unroll
            for (int mt = 0; mt < 4; ++mt) {
                acc[mt][nt] = __builtin_amdgcn_mfma_f32_16x16x32_bf16(za[mt], w0h, acc[mt][nt], 0,0,0);
                acc[mt][nt] = __builtin_amdgcn_mfma_f32_16x16x32_bf16(za[mt], w0l, acc[mt][nt], 0,0,0);
                acc[mt][nt] = __builtin_amdgcn_mfma_f32_16x16x32_bf16(zb[mt], w1h, acc[mt][nt], 0,0,0);
                acc[mt][nt] = __builtin_amdgcn_mfma_f32_16x16x32_bf16(zb[mt], w1l, acc[mt][nt], 0,0,0);
                acc[mt][nt] = __builtin_amdgcn_mfma_f32_16x16x32_bf16(zc[mt], w2h, acc[mt][nt], 0,0,0);
                acc[mt][nt] = __builtin_amdgcn_mfma_f32_16x16x32_bf16(zc[mt], w2l, acc[mt][nt], 0,0,0);
            }
        }
    }

#pragma unroll
    for (int mt = 0; mt < 4; ++mt) {
        float gg = gp[mt];
        gg += __shfl_xor(gg, 16, 64);
        gg += __shfl_xor(gg, 32, 64);
        if (w == 0 && quad == 0) gv[16*mt + il] = gg;
    }
    __syncthreads();
    if (tid < 64) gv[tid] = 1.0f / (1.0f + __expf(-(gv[tid] + bg[0])));
    __syncthreads();

#pragma unroll
    for (int nt = 0; nt < 4; ++nt) {
        const int col = w*64 + nt*16 + il;
        const float bfv = bf[col];
#pragma unroll
        for (int mt = 0; mt < 4; ++mt) {
#pragma unroll
            for (int b = 0; b < 4; ++b) {
                const int r = 16*mt + 4*quad + b;
                const float g = gv[r];
                const float cc = c2b[(size_t)r*DD + col];
                out[(row0 + r)*DD + col] = g * tanhf(acc[mt][nt][b] + bfv) + (1.f - g) * cc;
            }
        }
    }
}

extern "C" void kernel_launch(void* const* d_in, const int* in_sizes, int n_in,
                              void* d_out, int out_size, void* d_ws, size_t ws_size,
                              hipStream_t stream)
{
    const float* c1 = (const float*)d_in[0];
    const float* c2 = (const float*)d_in[1];
    const unsigned char* cmask = (const unsigned char*)d_in[2];
    const float* Wf = (const float*)d_in[3];
    const float* bf = (const float*)d_in[4];
    const float* Wg = (const float*)d_in[5];
    const float* bg = (const float*)d_in[6];

    const size_t aug_elems   = (size_t)16384 * 256;      // 4,194,304 floats
    const size_t frag_elems  = (size_t)98304;            // uints per Whi/Wlo buffer

    // 4-way layout (R1-proven): aug(=Op0) | Op2 | Op3 | mlp4 ; Op1 aliases d_out
    // (dead until fusion). Wfrag aliases Op2 (dead after combine).
    const size_t ml4_elems  = (size_t)4 * 16384 * 2;     // 131,072 floats
    const size_t need4      = (3*aug_elems + ml4_elems) * sizeof(float);   // 50,855,936 B

    // 2-way layout (R0/R2-proven): Op[2*aug] | mlp2 | aug ; Wfrag aliases Op.
    const size_t opart_elems = (size_t)2 * aug_elems;
    const size_t ml2_elems   = (size_t)2 * 16384 * 2;
    const size_t need2       = (opart_elems + ml2_elems + aug_elems) * sizeof(float); // 50,593,792 B

    float* wsf = (float*)d_ws;

    if (ws_size >= need4) {
        // ---- 4-way K-split, 8-wave blocks: 512 blocks x 512 thr -> 2 blocks/CU,
        //      16 waves/CU (VGPR 124 <= 128 cap from __launch_bounds__(512,4)) ----
        float* aug = wsf;                       // also partial 0
        float* Op2 = wsf + aug_elems;
        float* Op3 = wsf + 2*aug_elems;
        float* mlp = wsf + 3*aug_elems;
        float* Op0 = aug;
        float* Op1 = (float*)d_out;             // dead until fusion writes it
        unsigned* Whi = (unsigned*)Op2;         // prep runs after combine: Op2 dead
        unsigned* Wlo = Whi + frag_elems;
        float*    gw  = (float*)(Wlo + frag_elems);

        attn_kernel<<<dim3(512), dim3(512), 0, stream>>>(c1, c2, cmask,
                                                         Op0, Op1, Op2, Op3, mlp, 512, 1);
        combine_kernel<<<dim3(4096), dim3(256), 0, stream>>>(Op0, Op1, Op2, Op3, mlp, aug, 4);
        prep_kernel<<<dim3(385), dim3(256), 0, stream>>>(Wf, Wg, Whi, Wlo, gw);
        fusion_mfma<<<dim3(256), dim3(256), 0, stream>>>(c2, aug, Whi, Wlo, gw, bg, bf, (float*)d_out);
    } else if (ws_size >= need2) {
        // ---- 2-way K-split (R2 config) ----
        float* Op  = wsf;
        float* mlp = wsf + opart_elems;
        float* aug = mlp + ml2_elems;
        unsigned* Whi = (unsigned*)Op;
        unsigned* Wlo = Whi + frag_elems;
        float*    gw  = (float*)(Wlo + frag_elems);

        attn_kernel<<<dim3(256), dim3(512), 0, stream>>>(c1, c2, cmask,
                                                         Op, Op + aug_elems, Op, Op, mlp, 1024, 1);
        combine_kernel<<<dim3(4096), dim3(256), 0, stream>>>(Op, Op + aug_elems, Op, Op, mlp, aug, 2);
        prep_kernel<<<dim3(385), dim3(256), 0, stream>>>(Wf, Wg, Whi, Wlo, gw);
        fusion_mfma<<<dim3(256), dim3(256), 0, stream>>>(c2, aug, Whi, Wlo, gw, bg, bf, (float*)d_out);
    } else {
        // ---- no-split fallback: 128 blocks x 512 thr ----
        float* aug = wsf;
        float* mlp = wsf;
        unsigned* Whi = (unsigned*)(wsf + aug_elems);
        unsigned* Wlo = Whi + frag_elems;
        float*    gw  = (float*)(Wlo + frag_elems);

        attn_kernel<<<dim3(128), dim3(512), 0, stream>>>(c1, c2, cmask,
                                                         aug, aug, aug, aug, mlp, 2048, 0);
        prep_kernel<<<dim3(385), dim3(256), 0, stream>>>(Wf, Wg, Whi, Wlo, gw);
        fusion_mfma<<<dim3(256), dim3(256), 0, stream>>>(c2, aug, Whi, Wlo, gw, bg, bf, (float*)d_out);
    }
}

// Round 4
// 285.374 us; speedup vs baseline: 7.4850x; 7.4850x over previous
//
#include <hip/hip_runtime.h>
#include <math.h>

#define BB 8
#define LL 2048
#define DD 256

typedef float  f4_t __attribute__((ext_vector_type(4)));
typedef short  s8_t __attribute__((ext_vector_type(8)));

union S8U { s8_t v; unsigned u[4]; };

__device__ __forceinline__ unsigned bitsf(float x){ union{float f; unsigned u;} c; c.f=x; return c.u; }
__device__ __forceinline__ float fbits(unsigned u){ union{float f; unsigned u;} c; c.u=u; return c.f; }
// pack two fp32 -> two bf16 (truncate), elem0 in low half
__device__ __forceinline__ unsigned pkhi(float a, float b){ return (bitsf(a)>>16) | (bitsf(b)&0xffff0000u); }
// pack two fp32 -> two bf16 (round-nearest-ish)
__device__ __forceinline__ unsigned pkrn(float a, float b){
    unsigned ua = bitsf(a) + 0x8000u, ub = bitsf(b) + 0x8000u;
    return (ua>>16) | (ub&0xffff0000u);
}

// sigma: row e (0..31) of the key tile -> Vperm slot; makes P's MFMA C/D layout
// directly usable as the PV A-operand (slot k=8q+4a+b holds j=16a+4q+b).
__device__ __forceinline__ int vslot(int e){ return ((e>>2)&3)*8 + ((e>>4)<<2) + (e&3); }

// ---------------- MFMA flash attention — R4: R3 grid with R2's register budget ----------------
// R3 lesson: __launch_bounds__(512,4) caps VGPR at 128 -> massive scratch spills
// (FETCH 2.7 GB). But R3 also PROVED 2 blocks/CU co-residency happens (41% occ).
// Fix: keep the (512,2) compile (124 VGPR, no spills). 124*4 = 496 <= 512-reg
// SIMD pool -> HW hosts 4 waves/SIMD anyway; launch_bounds min-waves is only an
// allocator floor, not a residency cap. Grid 512 (8 bb x 16 qb x 4 K-quarters).
__global__ __launch_bounds__(512,2)
void attn_kernel(const float* __restrict__ c1, const float* __restrict__ c2,
                 const unsigned char* __restrict__ cmask,
                 float* __restrict__ o0, float* __restrict__ o1,
                 float* __restrict__ o2, float* __restrict__ o3,
                 float* __restrict__ mlp,
                 int klen, int split)
{
    __shared__ short Khi[32*264];
    __shared__ short Klo[32*264];
    __shared__ short Vp [256*34];

    const int tid  = threadIdx.x;
    const int lane = tid & 63;
    const int w    = tid >> 6;          // 0..7
    const int il   = lane & 15;
    const int quad = lane >> 4;
    const int col  = tid & 255;         // staging column (d-index)
    const int hr   = (tid >> 8) * 16;   // staging row base (0 or 16)

    const int blk  = blockIdx.x;
    const int bb   = blk & 7;
    const int qb   = (blk >> 3) & 15;
    const int half = split ? (blk >> 7) : 0;   // 0..3 when grid=512
    const int kb   = half * klen;

    float* ob = (half == 0) ? o0 : (half == 1) ? o1 : (half == 2) ? o2 : o3;

    const float* c1b = c1 + (size_t)bb * LL * DD;
    const float* c2b = c2 + (size_t)bb * LL * DD;
    const unsigned char* mb = cmask + (size_t)bb * LL;

    const int q0w = qb*128 + w*16;      // 16 q-rows per wave

    // Q fragments (hi/lo bf16 split), 1 n-tile per wave
    s8_t qh[8], ql[8];
    {
        const float* qp = c2b + (size_t)(q0w + il)*DD + quad*8;
#pragma unroll
        for (int kd = 0; kd < 8; ++kd) {
            float4 x0 = *(const float4*)(qp + kd*32);
            float4 x1 = *(const float4*)(qp + kd*32 + 4);
            float e[8] = {x0.x,x0.y,x0.z,x0.w,x1.x,x1.y,x1.z,x1.w};
            S8U h, l;
#pragma unroll
            for (int p2 = 0; p2 < 4; ++p2) {
                float a = e[2*p2], b = e[2*p2+1];
                h.u[p2] = pkhi(a, b);
                float alo = a - fbits(bitsf(a)&0xffff0000u);
                float blo = b - fbits(bitsf(b)&0xffff0000u);
                l.u[p2] = pkhi(alo, blo);
            }
            qh[kd] = h.v; ql[kd] = l.v;
        }
    }

    f4_t o[16];
#pragma unroll
    for (int n = 0; n < 16; ++n) o[n] = (f4_t)0.0f;
    float m_s = -INFINITY;
    float l_s = 0.f;

    const int NT = klen >> 5;
    float g[16];

    // initial K/V tile stage: each thread loads 16 rows of its column
#pragma unroll
    for (int e = 0; e < 16; ++e) g[e] = c1b[(size_t)(kb + hr + e)*DD + col];
#pragma unroll
    for (int e = 0; e < 16; ++e) {
        unsigned ub = bitsf(g[e]);
        Khi[(hr + e)*264 + col] = (short)(ub >> 16);
        float lo = g[e] - fbits(ub & 0xffff0000u);
        Klo[(hr + e)*264 + col] = (short)(bitsf(lo) >> 16);
    }
#pragma unroll
    for (int e = 0; e < 16; e += 2)
        ((unsigned*)Vp)[col*17 + (vslot(hr + e)>>1)] = pkrn(g[e], g[e+1]);
    __syncthreads();

    for (int kt = 0; kt < NT; ++kt) {
        const int k0 = kt << 5;
        if (kt + 1 < NT) {
#pragma unroll
            for (int e = 0; e < 16; ++e)
                g[e] = c1b[(size_t)(kb + k0 + 32 + hr + e)*DD + col];
        }

        f4_t acc[2];
        acc[0] = (f4_t)0.0f;
        acc[1] = (f4_t)0.0f;

#pragma unroll
        for (int kd = 0; kd < 8; ++kd) {
            s8_t ah0 = *(const s8_t*)&Khi[(il     )*264 + kd*32 + quad*8];
            s8_t ah1 = *(const s8_t*)&Khi[(16 + il)*264 + kd*32 + quad*8];
            s8_t al0 = *(const s8_t*)&Klo[(il     )*264 + kd*32 + quad*8];
            s8_t al1 = *(const s8_t*)&Klo[(16 + il)*264 + kd*32 + quad*8];
            acc[0] = __builtin_amdgcn_mfma_f32_16x16x32_bf16(ah0, qh[kd], acc[0], 0,0,0);
            acc[1] = __builtin_amdgcn_mfma_f32_16x16x32_bf16(ah1, qh[kd], acc[1], 0,0,0);
            acc[0] = __builtin_amdgcn_mfma_f32_16x16x32_bf16(al0, qh[kd], acc[0], 0,0,0);
            acc[1] = __builtin_amdgcn_mfma_f32_16x16x32_bf16(al1, qh[kd], acc[1], 0,0,0);
            acc[0] = __builtin_amdgcn_mfma_f32_16x16x32_bf16(ah0, ql[kd], acc[0], 0,0,0);
            acc[1] = __builtin_amdgcn_mfma_f32_16x16x32_bf16(ah1, ql[kd], acc[1], 0,0,0);
        }

        unsigned mu[2];
#pragma unroll
        for (int mj = 0; mj < 2; ++mj)
            mu[mj] = *(const unsigned*)(mb + kb + k0 + 16*mj + 4*quad);

        // online softmax for this wave's 16 q-rows (row = il after quad-reduce)
        const int ig = q0w + il;
        float mn = m_s;
        f4_t p[2];
#pragma unroll
        for (int mj = 0; mj < 2; ++mj) {
#pragma unroll
            for (int b = 0; b < 4; ++b) {
                int jg = kb + k0 + 16*mj + 4*quad + b;
                float s = acc[mj][b];
                bool dead = (((mu[mj] >> (8*b)) & 0xff) != 0) || (jg == ig);
                s = dead ? -INFINITY : s;
                p[mj][b] = s;
                mn = fmaxf(mn, s);
            }
        }
        mn = fmaxf(mn, __shfl_xor(mn, 16, 64));
        mn = fmaxf(mn, __shfl_xor(mn, 32, 64));
        float al = __expf(m_s - mn);
        float rs = 0.f;
#pragma unroll
        for (int mj = 0; mj < 2; ++mj) {
#pragma unroll
            for (int b = 0; b < 4; ++b) {
                float pe = __expf(p[mj][b] - mn);
                p[mj][b] = pe;
                rs += pe;
            }
        }
        rs += __shfl_xor(rs, 16, 64);
        rs += __shfl_xor(rs, 32, 64);
        l_s = l_s*al + rs;
        m_s = mn;

        // rescale running O
        {
            float am[4];
#pragma unroll
            for (int b = 0; b < 4; ++b) am[b] = __shfl(al, 4*quad + b, 64);
#pragma unroll
            for (int n = 0; n < 16; ++n) {
#pragma unroll
                for (int b = 0; b < 4; ++b) o[n][b] *= am[b];
            }
        }

        // pack P -> bf16 A-fragment
        s8_t ap;
        {
            S8U a;
            a.u[0] = pkrn(p[0][0], p[0][1]);
            a.u[1] = pkrn(p[0][2], p[0][3]);
            a.u[2] = pkrn(p[1][0], p[1][1]);
            a.u[3] = pkrn(p[1][2], p[1][3]);
            ap = a.v;
        }
#pragma unroll
        for (int n = 0; n < 16; ++n) {
            S8U bv;
#pragma unroll
            for (int dd = 0; dd < 4; ++dd)
                bv.u[dd] = ((const unsigned*)Vp)[(16*n + il)*17 + quad*4 + dd];
            o[n] = __builtin_amdgcn_mfma_f32_16x16x32_bf16(ap, bv.v, o[n], 0,0,0);
        }

        __syncthreads();
        if (kt + 1 < NT) {
#pragma unroll
            for (int e = 0; e < 16; ++e) {
                unsigned ub = bitsf(g[e]);
                Khi[(hr + e)*264 + col] = (short)(ub >> 16);
                float lo = g[e] - fbits(ub & 0xffff0000u);
                Klo[(hr + e)*264 + col] = (short)(bitsf(lo) >> 16);
            }
#pragma unroll
            for (int e = 0; e < 16; e += 2)
                ((unsigned*)Vp)[col*17 + (vslot(hr + e)>>1)] = pkrn(g[e], g[e+1]);
        }
        __syncthreads();
    }

    const int rbq = bb*LL + q0w;
    if (split) {
        const int rbase = rbq + 4*quad;
#pragma unroll
        for (int n = 0; n < 16; ++n) {
            const int d = 16*n + il;
#pragma unroll
            for (int b = 0; b < 4; ++b)
                ob[(size_t)(rbase + b)*DD + d] = o[n][b];
        }
        if (lane < 16) {
            int r = rbq + lane;
            *(float2*)(&mlp[((size_t)half*16384 + r)*2]) = make_float2(m_s, l_s);
        }
    } else {
        float invl[4];
#pragma unroll
        for (int b = 0; b < 4; ++b) invl[b] = 1.0f / __shfl(l_s, 4*quad + b, 64);
        const int rbase = rbq + 4*quad;
#pragma unroll
        for (int n = 0; n < 16; ++n) {
            const int d = 16*n + il;
#pragma unroll
            for (int b = 0; b < 4; ++b)
                ob[(size_t)(rbase + b)*DD + d] = o[n][b] * invl[b];
        }
    }
}

// ---------------- split-K flash combine (ns-way, uniform branch) ----------------
// partial0 may alias aug (each thread reads its own element then writes the
// same element -> no hazard).
__global__ __launch_bounds__(256)
void combine_kernel(const float* __restrict__ o0, const float* __restrict__ o1,
                    const float* __restrict__ o2, const float* __restrict__ o3,
                    const float* __restrict__ mlp, float* __restrict__ aug, int ns)
{
    int t = blockIdx.x*256 + threadIdx.x;
    int r = t >> 6, c = (t & 63) << 2;

    float m[4], l[4];
#pragma unroll
    for (int h = 0; h < 4; ++h) {
        if (h < ns) {
            m[h] = mlp[((size_t)h*16384 + r)*2];
            l[h] = mlp[((size_t)h*16384 + r)*2 + 1];
        } else { m[h] = -INFINITY; l[h] = 0.f; }
    }
    float M = fmaxf(fmaxf(m[0], m[1]), fmaxf(m[2], m[3]));

    f4_t res = (f4_t)0.0f;
    float den = 0.f;
#pragma unroll
    for (int h = 0; h < 4; ++h) {
        if (h < ns) {
            float a = __expf(m[h] - M);
            den += a * l[h];
            const float* oh = (h == 0) ? o0 : (h == 1) ? o1 : (h == 2) ? o2 : o3;
            f4_t x = *(const f4_t*)(oh + (size_t)r*DD + c);
            res += x * a;
        }
    }
    res *= (1.0f / den);
    *(f4_t*)(aug + (size_t)r*DD + c) = res;
}

// ---------------- prep (unchanged) ----------------
__global__ __launch_bounds__(256)
void prep_kernel(const float* __restrict__ Wf, const float* __restrict__ Wg,
                 unsigned* __restrict__ Whi, unsigned* __restrict__ Wlo,
                 float* __restrict__ gw)
{
    if (blockIdx.x == 384) {
#pragma unroll
        for (int i = 0; i < 3; ++i) {
            int kl = threadIdx.x;
            float v = (i == 0) ? (Wg[kl] + Wg[768 + kl])
                    : (i == 1) ? (Wg[256 + kl] - Wg[768 + kl])
                               :  Wg[512 + kl];
            gw[i*256 + kl] = v;
        }
        return;
    }
    int t    = blockIdx.x*256 + threadIdx.x;    // [0, 98304)
    int p    = t & 3;
    int lane = (t >> 2) & 63;
    int nt   = (t >> 8) & 15;
    int g2   = t >> 12;                          // kc*3 + seg, [0,24)
    int seg  = g2 % 3;
    int kc   = g2 / 3;
    int kl   = kc*32 + (lane >> 4)*8 + 2*p;
    int n    = nt*16 + (lane & 15);
    float v0, v1;
    if (seg == 0) {
        v0 = Wf[(size_t)kl*DD + n]       + Wf[(size_t)(768 + kl)*DD + n];
        v1 = Wf[(size_t)(kl + 1)*DD + n] + Wf[(size_t)(769 + kl)*DD + n];
    } else if (seg == 1) {
        v0 = Wf[(size_t)(256 + kl)*DD + n] - Wf[(size_t)(768 + kl)*DD + n];
        v1 = Wf[(size_t)(257 + kl)*DD + n] - Wf[(size_t)(769 + kl)*DD + n];
    } else {
        v0 = Wf[(size_t)(512 + kl)*DD + n];
        v1 = Wf[(size_t)(513 + kl)*DD + n];
    }
    Whi[t] = pkhi(v0, v1);
    float l0 = v0 - fbits(bitsf(v0) & 0xffff0000u);
    float l1 = v1 - fbits(bitsf(v1) & 0xffff0000u);
    Wlo[t] = pkrn(l0, l1);
}

// ---------------- MFMA fusion (unchanged) ----------------
__global__ __launch_bounds__(256,1)
void fusion_mfma(const float* __restrict__ c2, const float* __restrict__ aug,
                 const unsigned* __restrict__ Whi, const unsigned* __restrict__ Wlo,
                 const float* __restrict__ gw, const float* __restrict__ bg,
                 const float* __restrict__ bf, float* __restrict__ out)
{
    __shared__ float gwL[768];
    __shared__ float gv[64];

    const int tid  = threadIdx.x;
    const int lane = tid & 63;
    const int w    = tid >> 6;
    const int il   = lane & 15;
    const int quad = lane >> 4;
    const size_t row0 = (size_t)blockIdx.x * 64;

    const float* c2b  = c2 + row0*DD;
    const float* augb = aug + row0*DD;

    for (int i = tid; i < 768; i += 256) gwL[i] = gw[i];
    __syncthreads();

    f4_t acc[4][4];
#pragma unroll
    for (int mt = 0; mt < 4; ++mt)
#pragma unroll
        for (int nt = 0; nt < 4; ++nt) acc[mt][nt] = (f4_t)0.0f;
    float gp[4] = {0.f, 0.f, 0.f, 0.f};

    for (int kc = 0; kc < 8; ++kc) {
        s8_t za[4], zb[4], zc[4];
        const int c0 = kc*32 + quad*8;
#pragma unroll
        for (int mt = 0; mt < 4; ++mt) {
            const float* pr = c2b  + (size_t)(16*mt + il)*DD + c0;
            const float* pu = augb + (size_t)(16*mt + il)*DD + c0;
            float4 a0 = *(const float4*)pr, a1 = *(const float4*)(pr + 4);
            float4 u0 = *(const float4*)pu, u1 = *(const float4*)(pu + 4);
            float ea[8] = {a0.x,a0.y,a0.z,a0.w,a1.x,a1.y,a1.z,a1.w};
            float eu[8] = {u0.x,u0.y,u0.z,u0.w,u1.x,u1.y,u1.z,u1.w};
#pragma unroll
            for (int j = 0; j < 8; ++j)
                gp[mt] += ea[j]*gwL[c0+j] + eu[j]*gwL[256+c0+j] + (ea[j]*eu[j])*gwL[512+c0+j];
            S8U A, U, Pd;
#pragma unroll
            for (int p = 0; p < 4; ++p) {
                A.u[p]  = pkrn(ea[2*p], ea[2*p+1]);
                U.u[p]  = pkrn(eu[2*p], eu[2*p+1]);
                Pd.u[p] = pkrn(ea[2*p]*eu[2*p], ea[2*p+1]*eu[2*p+1]);
            }
            za[mt] = A.v; zb[mt] = U.v; zc[mt] = Pd.v;
        }
#pragma unroll
        for (int nt = 0; nt < 4; ++nt) {
            const int ntg = w*4 + nt;
            const size_t f0 = ((size_t)((kc*3 + 0)*16 + ntg)*64 + lane)*4;
            const size_t f1 = ((size_t)((kc*3 + 1)*16 + ntg)*64 + lane)*4;
            const size_t f2 = ((size_t)((kc*3 + 2)*16 + ntg)*64 + lane)*4;
            s8_t w0h = *(const s8_t*)(Whi + f0), w0l = *(const s8_t*)(Wlo + f0);
            s8_t w1h = *(const s8_t*)(Whi + f1), w1l = *(const s8_t*)(Wlo + f1);
            s8_t w2h = *(const s8_t*)(Whi + f2), w2l = *(const s8_t*)(Wlo + f2);
#pragma unroll
            for (int mt = 0; mt < 4; ++mt) {
                acc[mt][nt] = __builtin_amdgcn_mfma_f32_16x16x32_bf16(za[mt], w0h, acc[mt][nt], 0,0,0);
                acc[mt][nt] = __builtin_amdgcn_mfma_f32_16x16x32_bf16(za[mt], w0l, acc[mt][nt], 0,0,0);
                acc[mt][nt] = __builtin_amdgcn_mfma_f32_16x16x32_bf16(zb[mt], w1h, acc[mt][nt], 0,0,0);
                acc[mt][nt] = __builtin_amdgcn_mfma_f32_16x16x32_bf16(zb[mt], w1l, acc[mt][nt], 0,0,0);
                acc[mt][nt] = __builtin_amdgcn_mfma_f32_16x16x32_bf16(zc[mt], w2h, acc[mt][nt], 0,0,0);
                acc[mt][nt] = __builtin_amdgcn_mfma_f32_16x16x32_bf16(zc[mt], w2l, acc[mt][nt], 0,0,0);
            }
        }
    }

#pragma unroll
    for (int mt = 0; mt < 4; ++mt) {
        float gg = gp[mt];
        gg += __shfl_xor(gg, 16, 64);
        gg += __shfl_xor(gg, 32, 64);
        if (w == 0 && quad == 0) gv[16*mt + il] = gg;
    }
    __syncthreads();
    if (tid < 64) gv[tid] = 1.0f / (1.0f + __expf(-(gv[tid] + bg[0])));
    __syncthreads();

#pragma unroll
    for (int nt = 0; nt < 4; ++nt) {
        const int col = w*64 + nt*16 + il;
        const float bfv = bf[col];
#pragma unroll
        for (int mt = 0; mt < 4; ++mt) {
#pragma unroll
            for (int b = 0; b < 4; ++b) {
                const int r = 16*mt + 4*quad + b;
                const float g = gv[r];
                const float cc = c2b[(size_t)r*DD + col];
                out[(row0 + r)*DD + col] = g * tanhf(acc[mt][nt][b] + bfv) + (1.f - g) * cc;
            }
        }
    }
}

extern "C" void kernel_launch(void* const* d_in, const int* in_sizes, int n_in,
                              void* d_out, int out_size, void* d_ws, size_t ws_size,
                              hipStream_t stream)
{
    const float* c1 = (const float*)d_in[0];
    const float* c2 = (const float*)d_in[1];
    const unsigned char* cmask = (const unsigned char*)d_in[2];
    const float* Wf = (const float*)d_in[3];
    const float* bf = (const float*)d_in[4];
    const float* Wg = (const float*)d_in[5];
    const float* bg = (const float*)d_in[6];

    const size_t aug_elems   = (size_t)16384 * 256;      // 4,194,304 floats
    const size_t frag_elems  = (size_t)98304;            // uints per Whi/Wlo buffer

    // 4-way layout: aug(=Op0) | Op2 | Op3 | mlp4 ; Op1 aliases d_out
    // (dead until fusion). Wfrag aliases Op2 (dead after combine).
    const size_t ml4_elems  = (size_t)4 * 16384 * 2;     // 131,072 floats
    const size_t need4      = (3*aug_elems + ml4_elems) * sizeof(float);   // 50,855,936 B

    // 2-way layout (R2-proven): Op[2*aug] | mlp2 | aug ; Wfrag aliases Op.
    const size_t opart_elems = (size_t)2 * aug_elems;
    const size_t ml2_elems   = (size_t)2 * 16384 * 2;
    const size_t need2       = (opart_elems + ml2_elems + aug_elems) * sizeof(float); // 50,593,792 B

    float* wsf = (float*)d_ws;

    if (ws_size >= need4) {
        // ---- 4-way K-split, 8-wave blocks, (512,2) compile: 512 blocks ->
        //      2 blocks/CU, 16 waves/CU, no spills ----
        float* aug = wsf;                       // also partial 0
        float* Op2 = wsf + aug_elems;
        float* Op3 = wsf + 2*aug_elems;
        float* mlp = wsf + 3*aug_elems;
        float* Op0 = aug;
        float* Op1 = (float*)d_out;             // dead until fusion writes it
        unsigned* Whi = (unsigned*)Op2;         // prep runs after combine: Op2 dead
        unsigned* Wlo = Whi + frag_elems;
        float*    gw  = (float*)(Wlo + frag_elems);

        attn_kernel<<<dim3(512), dim3(512), 0, stream>>>(c1, c2, cmask,
                                                         Op0, Op1, Op2, Op3, mlp, 512, 1);
        combine_kernel<<<dim3(4096), dim3(256), 0, stream>>>(Op0, Op1, Op2, Op3, mlp, aug, 4);
        prep_kernel<<<dim3(385), dim3(256), 0, stream>>>(Wf, Wg, Whi, Wlo, gw);
        fusion_mfma<<<dim3(256), dim3(256), 0, stream>>>(c2, aug, Whi, Wlo, gw, bg, bf, (float*)d_out);
    } else if (ws_size >= need2) {
        // ---- 2-way K-split (R2 config) ----
        float* Op  = wsf;
        float* mlp = wsf + opart_elems;
        float* aug = mlp + ml2_elems;
        unsigned* Whi = (unsigned*)Op;
        unsigned* Wlo = Whi + frag_elems;
        float*    gw  = (float*)(Wlo + frag_elems);

        attn_kernel<<<dim3(256), dim3(512), 0, stream>>>(c1, c2, cmask,
                                                         Op, Op + aug_elems, Op, Op, mlp, 1024, 1);
        combine_kernel<<<dim3(4096), dim3(256), 0, stream>>>(Op, Op + aug_elems, Op, Op, mlp, aug, 2);
        prep_kernel<<<dim3(385), dim3(256), 0, stream>>>(Wf, Wg, Whi, Wlo, gw);
        fusion_mfma<<<dim3(256), dim3(256), 0, stream>>>(c2, aug, Whi, Wlo, gw, bg, bf, (float*)d_out);
    } else {
        // ---- no-split fallback: 128 blocks x 512 thr ----
        float* aug = wsf;
        float* mlp = wsf;
        unsigned* Whi = (unsigned*)(wsf + aug_elems);
        unsigned* Wlo = Whi + frag_elems;
        float*    gw  = (float*)(Wlo + frag_elems);

        attn_kernel<<<dim3(128), dim3(512), 0, stream>>>(c1, c2, cmask,
                                                         aug, aug, aug, aug, mlp, 2048, 0);
        prep_kernel<<<dim3(385), dim3(256), 0, stream>>>(Wf, Wg, Whi, Wlo, gw);
        fusion_mfma<<<dim3(256), dim3(256), 0, stream>>>(c2, aug, Whi, Wlo, gw, bg, bf, (float*)d_out);
    }
}

// Round 5
// 251.393 us; speedup vs baseline: 8.4967x; 1.1352x over previous
//
#include <hip/hip_runtime.h>
#include <math.h>

#define BB 8
#define LL 2048
#define DD 256

typedef float  f4_t __attribute__((ext_vector_type(4)));
typedef short  s8_t __attribute__((ext_vector_type(8)));

union S8U { s8_t v; unsigned u[4]; };

__device__ __forceinline__ unsigned bitsf(float x){ union{float f; unsigned u;} c; c.f=x; return c.u; }
__device__ __forceinline__ float fbits(unsigned u){ union{float f; unsigned u;} c; c.u=u; return c.f; }
// pack two fp32 -> two bf16 (truncate), elem0 in low half
__device__ __forceinline__ unsigned pkhi(float a, float b){ return (bitsf(a)>>16) | (bitsf(b)&0xffff0000u); }
// pack two fp32 -> two bf16 (round-nearest-ish)
__device__ __forceinline__ unsigned pkrn(float a, float b){
    unsigned ua = bitsf(a) + 0x8000u, ub = bitsf(b) + 0x8000u;
    return (ua>>16) | (ub&0xffff0000u);
}

// sigma: row e (0..31) of the key tile -> Vperm slot; makes P's MFMA C/D layout
// directly usable as the PV A-operand (slot k=8q+4a+b holds j=16a+4q+b).
__device__ __forceinline__ int vslot(int e){ return ((e>>2)&3)*8 + ((e>>4)<<2) + (e&3); }

// ---------------- MFMA flash attention — R5: exact R2 config (proven 124 us) ----------------
// R4 lesson: unified VGPR+AGPR footprint is ~188 (124 arch + 64 acc) -> 2 waves/SIMD
// is the HW cap for this shape; 4-way split buys nothing. 2-way split, 256 blocks
// x 512 thr, 16 q-rows/wave.
__global__ __launch_bounds__(512,2)
void attn_kernel(const float* __restrict__ c1, const float* __restrict__ c2,
                 const unsigned char* __restrict__ cmask,
                 float* __restrict__ o0, float* __restrict__ o1,
                 float* __restrict__ mlp,
                 int klen, int split)
{
    __shared__ short Khi[32*264];
    __shared__ short Klo[32*264];
    __shared__ short Vp [256*34];

    const int tid  = threadIdx.x;
    const int lane = tid & 63;
    const int w    = tid >> 6;          // 0..7
    const int il   = lane & 15;
    const int quad = lane >> 4;
    const int col  = tid & 255;         // staging column (d-index)
    const int hr   = (tid >> 8) * 16;   // staging row base (0 or 16)

    const int blk  = blockIdx.x;
    const int bb   = blk & 7;
    const int qb   = (blk >> 3) & 15;
    const int half = split ? ((blk >> 7) & 1) : 0;
    const int kb   = half * klen;

    float* ob = half ? o1 : o0;

    const float* c1b = c1 + (size_t)bb * LL * DD;
    const float* c2b = c2 + (size_t)bb * LL * DD;
    const unsigned char* mb = cmask + (size_t)bb * LL;

    const int q0w = qb*128 + w*16;      // 16 q-rows per wave

    // Q fragments (hi/lo bf16 split), 1 n-tile per wave
    s8_t qh[8], ql[8];
    {
        const float* qp = c2b + (size_t)(q0w + il)*DD + quad*8;
#pragma unroll
        for (int kd = 0; kd < 8; ++kd) {
            float4 x0 = *(const float4*)(qp + kd*32);
            float4 x1 = *(const float4*)(qp + kd*32 + 4);
            float e[8] = {x0.x,x0.y,x0.z,x0.w,x1.x,x1.y,x1.z,x1.w};
            S8U h, l;
#pragma unroll
            for (int p2 = 0; p2 < 4; ++p2) {
                float a = e[2*p2], b = e[2*p2+1];
                h.u[p2] = pkhi(a, b);
                float alo = a - fbits(bitsf(a)&0xffff0000u);
                float blo = b - fbits(bitsf(b)&0xffff0000u);
                l.u[p2] = pkhi(alo, blo);
            }
            qh[kd] = h.v; ql[kd] = l.v;
        }
    }

    f4_t o[16];
#pragma unroll
    for (int n = 0; n < 16; ++n) o[n] = (f4_t)0.0f;
    float m_s = -INFINITY;
    float l_s = 0.f;

    const int NT = klen >> 5;
    float g[16];

    // initial K/V tile stage: each thread loads 16 rows of its column
#pragma unroll
    for (int e = 0; e < 16; ++e) g[e] = c1b[(size_t)(kb + hr + e)*DD + col];
#pragma unroll
    for (int e = 0; e < 16; ++e) {
        unsigned ub = bitsf(g[e]);
        Khi[(hr + e)*264 + col] = (short)(ub >> 16);
        float lo = g[e] - fbits(ub & 0xffff0000u);
        Klo[(hr + e)*264 + col] = (short)(bitsf(lo) >> 16);
    }
#pragma unroll
    for (int e = 0; e < 16; e += 2)
        ((unsigned*)Vp)[col*17 + (vslot(hr + e)>>1)] = pkrn(g[e], g[e+1]);
    __syncthreads();

    for (int kt = 0; kt < NT; ++kt) {
        const int k0 = kt << 5;
        if (kt + 1 < NT) {
#pragma unroll
            for (int e = 0; e < 16; ++e)
                g[e] = c1b[(size_t)(kb + k0 + 32 + hr + e)*DD + col];
        }

        f4_t acc[2];
        acc[0] = (f4_t)0.0f;
        acc[1] = (f4_t)0.0f;

#pragma unroll
        for (int kd = 0; kd < 8; ++kd) {
            s8_t ah0 = *(const s8_t*)&Khi[(il     )*264 + kd*32 + quad*8];
            s8_t ah1 = *(const s8_t*)&Khi[(16 + il)*264 + kd*32 + quad*8];
            s8_t al0 = *(const s8_t*)&Klo[(il     )*264 + kd*32 + quad*8];
            s8_t al1 = *(const s8_t*)&Klo[(16 + il)*264 + kd*32 + quad*8];
            acc[0] = __builtin_amdgcn_mfma_f32_16x16x32_bf16(ah0, qh[kd], acc[0], 0,0,0);
            acc[1] = __builtin_amdgcn_mfma_f32_16x16x32_bf16(ah1, qh[kd], acc[1], 0,0,0);
            acc[0] = __builtin_amdgcn_mfma_f32_16x16x32_bf16(al0, qh[kd], acc[0], 0,0,0);
            acc[1] = __builtin_amdgcn_mfma_f32_16x16x32_bf16(al1, qh[kd], acc[1], 0,0,0);
            acc[0] = __builtin_amdgcn_mfma_f32_16x16x32_bf16(ah0, ql[kd], acc[0], 0,0,0);
            acc[1] = __builtin_amdgcn_mfma_f32_16x16x32_bf16(ah1, ql[kd], acc[1], 0,0,0);
        }

        unsigned mu[2];
#pragma unroll
        for (int mj = 0; mj < 2; ++mj)
            mu[mj] = *(const unsigned*)(mb + kb + k0 + 16*mj + 4*quad);

        // online softmax for this wave's 16 q-rows (row = il after quad-reduce)
        const int ig = q0w + il;
        float mn = m_s;
        f4_t p[2];
#pragma unroll
        for (int mj = 0; mj < 2; ++mj) {
#pragma unroll
            for (int b = 0; b < 4; ++b) {
                int jg = kb + k0 + 16*mj + 4*quad + b;
                float s = acc[mj][b];
                bool dead = (((mu[mj] >> (8*b)) & 0xff) != 0) || (jg == ig);
                s = dead ? -INFINITY : s;
                p[mj][b] = s;
                mn = fmaxf(mn, s);
            }
        }
        mn = fmaxf(mn, __shfl_xor(mn, 16, 64));
        mn = fmaxf(mn, __shfl_xor(mn, 32, 64));
        float al = __expf(m_s - mn);
        float rs = 0.f;
#pragma unroll
        for (int mj = 0; mj < 2; ++mj) {
#pragma unroll
            for (int b = 0; b < 4; ++b) {
                float pe = __expf(p[mj][b] - mn);
                p[mj][b] = pe;
                rs += pe;
            }
        }
        rs += __shfl_xor(rs, 16, 64);
        rs += __shfl_xor(rs, 32, 64);
        l_s = l_s*al + rs;
        m_s = mn;

        // rescale running O
        {
            float am[4];
#pragma unroll
            for (int b = 0; b < 4; ++b) am[b] = __shfl(al, 4*quad + b, 64);
#pragma unroll
            for (int n = 0; n < 16; ++n) {
#pragma unroll
                for (int b = 0; b < 4; ++b) o[n][b] *= am[b];
            }
        }

        // pack P -> bf16 A-fragment
        s8_t ap;
        {
            S8U a;
            a.u[0] = pkrn(p[0][0], p[0][1]);
            a.u[1] = pkrn(p[0][2], p[0][3]);
            a.u[2] = pkrn(p[1][0], p[1][1]);
            a.u[3] = pkrn(p[1][2], p[1][3]);
            ap = a.v;
        }
#pragma unroll
        for (int n = 0; n < 16; ++n) {
            S8U bv;
#pragma unroll
            for (int dd = 0; dd < 4; ++dd)
                bv.u[dd] = ((const unsigned*)Vp)[(16*n + il)*17 + quad*4 + dd];
            o[n] = __builtin_amdgcn_mfma_f32_16x16x32_bf16(ap, bv.v, o[n], 0,0,0);
        }

        __syncthreads();
        if (kt + 1 < NT) {
#pragma unroll
            for (int e = 0; e < 16; ++e) {
                unsigned ub = bitsf(g[e]);
                Khi[(hr + e)*264 + col] = (short)(ub >> 16);
                float lo = g[e] - fbits(ub & 0xffff0000u);
                Klo[(hr + e)*264 + col] = (short)(bitsf(lo) >> 16);
            }
#pragma unroll
            for (int e = 0; e < 16; e += 2)
                ((unsigned*)Vp)[col*17 + (vslot(hr + e)>>1)] = pkrn(g[e], g[e+1]);
        }
        __syncthreads();
    }

    const int rbq = bb*LL + q0w;
    if (split) {
        const int rbase = rbq + 4*quad;
#pragma unroll
        for (int n = 0; n < 16; ++n) {
            const int d = 16*n + il;
#pragma unroll
            for (int b = 0; b < 4; ++b)
                ob[(size_t)(rbase + b)*DD + d] = o[n][b];
        }
        if (lane < 16) {
            int r = rbq + lane;
            *(float2*)(&mlp[((size_t)half*16384 + r)*2]) = make_float2(m_s, l_s);
        }
    } else {
        float invl[4];
#pragma unroll
        for (int b = 0; b < 4; ++b) invl[b] = 1.0f / __shfl(l_s, 4*quad + b, 64);
        const int rbase = rbq + 4*quad;
#pragma unroll
        for (int n = 0; n < 16; ++n) {
            const int d = 16*n + il;
#pragma unroll
            for (int b = 0; b < 4; ++b)
                ob[(size_t)(rbase + b)*DD + d] = o[n][b] * invl[b];
        }
    }
}

// ---------------- split-K flash combine (2-way) ----------------
__global__ __launch_bounds__(256)
void combine_kernel(const float* __restrict__ o0, const float* __restrict__ o1,
                    const float* __restrict__ mlp, float* __restrict__ aug)
{
    int t = blockIdx.x*256 + threadIdx.x;
    int r = t >> 6, c = (t & 63) << 2;
    float m0 = mlp[(size_t)r*2],           l0 = mlp[(size_t)r*2 + 1];
    float m1 = mlp[((size_t)16384 + r)*2], l1 = mlp[((size_t)16384 + r)*2 + 1];
    float M  = fmaxf(m0, m1);
    float a0 = __expf(m0 - M), a1 = __expf(m1 - M);
    float inv = 1.0f / (a0*l0 + a1*l1);
    f4_t x0 = *(const f4_t*)(o0 + (size_t)r*DD + c);
    f4_t x1 = *(const f4_t*)(o1 + (size_t)r*DD + c);
    f4_t res = (x0*a0 + x1*a1) * inv;
    *(f4_t*)(aug + (size_t)r*DD + c) = res;
}

// ---------------- prep (unchanged) ----------------
__global__ __launch_bounds__(256)
void prep_kernel(const float* __restrict__ Wf, const float* __restrict__ Wg,
                 unsigned* __restrict__ Whi, unsigned* __restrict__ Wlo,
                 float* __restrict__ gw)
{
    if (blockIdx.x == 384) {
#pragma unroll
        for (int i = 0; i < 3; ++i) {
            int kl = threadIdx.x;
            float v = (i == 0) ? (Wg[kl] + Wg[768 + kl])
                    : (i == 1) ? (Wg[256 + kl] - Wg[768 + kl])
                               :  Wg[512 + kl];
            gw[i*256 + kl] = v;
        }
        return;
    }
    int t    = blockIdx.x*256 + threadIdx.x;    // [0, 98304)
    int p    = t & 3;
    int lane = (t >> 2) & 63;
    int nt   = (t >> 8) & 15;
    int g2   = t >> 12;                          // kc*3 + seg, [0,24)
    int seg  = g2 % 3;
    int kc   = g2 / 3;
    int kl   = kc*32 + (lane >> 4)*8 + 2*p;
    int n    = nt*16 + (lane & 15);
    float v0, v1;
    if (seg == 0) {
        v0 = Wf[(size_t)kl*DD + n]       + Wf[(size_t)(768 + kl)*DD + n];
        v1 = Wf[(size_t)(kl + 1)*DD + n] + Wf[(size_t)(769 + kl)*DD + n];
    } else if (seg == 1) {
        v0 = Wf[(size_t)(256 + kl)*DD + n] - Wf[(size_t)(768 + kl)*DD + n];
        v1 = Wf[(size_t)(257 + kl)*DD + n] - Wf[(size_t)(769 + kl)*DD + n];
    } else {
        v0 = Wf[(size_t)(512 + kl)*DD + n];
        v1 = Wf[(size_t)(513 + kl)*DD + n];
    }
    Whi[t] = pkhi(v0, v1);
    float l0 = v0 - fbits(bitsf(v0) & 0xffff0000u);
    float l1 = v1 - fbits(bitsf(v1) & 0xffff0000u);
    Wlo[t] = pkrn(l0, l1);
}

// ---------------- MFMA fusion — R5: 8-wave blocks, 32 cols/wave ----------------
// Old shape: 256 thr (4 waves), each wave 64 cols, acc[4][4] -> 4 waves/CU =
// 12.5% occupancy, latency-bound (est. ~115 us, bigger than attn!). New shape:
// 512 thr (8 waves), each wave 32 cols (nt=2, ntg = w*2+nt), acc[4][2] = 32 regs,
// ~140 unified regs -> 2 waves/SIMD -> 8 waves/CU. Weight traffic per block
// unchanged (full W once per block, 201 MB total, L2-resident). Input redundancy
// 4x -> 8x but L2-cached. No allocator cap (512,1) to avoid R3-style spills.
__global__ __launch_bounds__(512,1)
void fusion_mfma(const float* __restrict__ c2, const float* __restrict__ aug,
                 const unsigned* __restrict__ Whi, const unsigned* __restrict__ Wlo,
                 const float* __restrict__ gw, const float* __restrict__ bg,
                 const float* __restrict__ bf, float* __restrict__ out)
{
    __shared__ float gwL[768];
    __shared__ float gv[64];

    const int tid  = threadIdx.x;
    const int lane = tid & 63;
    const int w    = tid >> 6;          // 0..7
    const int il   = lane & 15;
    const int quad = lane >> 4;
    const size_t row0 = (size_t)blockIdx.x * 64;

    const float* c2b  = c2 + row0*DD;
    const float* augb = aug + row0*DD;

    for (int i = tid; i < 768; i += 512) gwL[i] = gw[i];
    __syncthreads();

    f4_t acc[4][2];
#pragma unroll
    for (int mt = 0; mt < 4; ++mt)
#pragma unroll
        for (int nt = 0; nt < 2; ++nt) acc[mt][nt] = (f4_t)0.0f;
    float gp[4] = {0.f, 0.f, 0.f, 0.f};

    for (int kc = 0; kc < 8; ++kc) {
        s8_t za[4], zb[4], zc[4];
        const int c0 = kc*32 + quad*8;
#pragma unroll
        for (int mt = 0; mt < 4; ++mt) {
            const float* pr = c2b  + (size_t)(16*mt + il)*DD + c0;
            const float* pu = augb + (size_t)(16*mt + il)*DD + c0;
            float4 a0 = *(const float4*)pr, a1 = *(const float4*)(pr + 4);
            float4 u0 = *(const float4*)pu, u1 = *(const float4*)(pu + 4);
            float ea[8] = {a0.x,a0.y,a0.z,a0.w,a1.x,a1.y,a1.z,a1.w};
            float eu[8] = {u0.x,u0.y,u0.z,u0.w,u1.x,u1.y,u1.z,u1.w};
#pragma unroll
            for (int j = 0; j < 8; ++j)
                gp[mt] += ea[j]*gwL[c0+j] + eu[j]*gwL[256+c0+j] + (ea[j]*eu[j])*gwL[512+c0+j];
            S8U A, U, Pd;
#pragma unroll
            for (int p = 0; p < 4; ++p) {
                A.u[p]  = pkrn(ea[2*p], ea[2*p+1]);
                U.u[p]  = pkrn(eu[2*p], eu[2*p+1]);
                Pd.u[p] = pkrn(ea[2*p]*eu[2*p], ea[2*p+1]*eu[2*p+1]);
            }
            za[mt] = A.v; zb[mt] = U.v; zc[mt] = Pd.v;
        }
#pragma unroll
        for (int nt = 0; nt < 2; ++nt) {
            const int ntg = w*2 + nt;     // 0..15
            const size_t f0 = ((size_t)((kc*3 + 0)*16 + ntg)*64 + lane)*4;
            const size_t f1 = ((size_t)((kc*3 + 1)*16 + ntg)*64 + lane)*4;
            const size_t f2 = ((size_t)((kc*3 + 2)*16 + ntg)*64 + lane)*4;
            s8_t w0h = *(const s8_t*)(Whi + f0), w0l = *(const s8_t*)(Wlo + f0);
            s8_t w1h = *(const s8_t*)(Whi + f1), w1l = *(const s8_t*)(Wlo + f1);
            s8_t w2h = *(const s8_t*)(Whi + f2), w2l = *(const s8_t*)(Wlo + f2);
#pragma unroll
            for (int mt = 0; mt < 4; ++mt) {
                acc[mt][nt] = __builtin_amdgcn_mfma_f32_16x16x32_bf16(za[mt], w0h, acc[mt][nt], 0,0,0);
                acc[mt][nt] = __builtin_amdgcn_mfma_f32_16x16x32_bf16(za[mt], w0l, acc[mt][nt], 0,0,0);
                acc[mt][nt] = __builtin_amdgcn_mfma_f32_16x16x32_bf16(zb[mt], w1h, acc[mt][nt], 0,0,0);
                acc[mt][nt] = __builtin_amdgcn_mfma_f32_16x16x32_bf16(zb[mt], w1l, acc[mt][nt], 0,0,0);
                acc[mt][nt] = __builtin_amdgcn_mfma_f32_16x16x32_bf16(zc[mt], w2h, acc[mt][nt], 0,0,0);
                acc[mt][nt] = __builtin_amdgcn_mfma_f32_16x16x32_bf16(zc[mt], w2l, acc[mt][nt], 0,0,0);
            }
        }
    }

    // gate reduce over the 4 quad lanes; wave 0 publishes (all waves computed
    // identical gp since the input loop is nt-independent)
#pragma unroll
    for (int mt = 0; mt < 4; ++mt) {
        float gg = gp[mt];
        gg += __shfl_xor(gg, 16, 64);
        gg += __shfl_xor(gg, 32, 64);
        if (w == 0 && quad == 0) gv[16*mt + il] = gg;
    }
    __syncthreads();
    if (tid < 64) gv[tid] = 1.0f / (1.0f + __expf(-(gv[tid] + bg[0])));
    __syncthreads();

    // epilogue: row = 16mt + 4quad + b, col = 32w + 16nt + il
#pragma unroll
    for (int nt = 0; nt < 2; ++nt) {
        const int col = w*32 + nt*16 + il;
        const float bfv = bf[col];
#pragma unroll
        for (int mt = 0; mt < 4; ++mt) {
#pragma unroll
            for (int b = 0; b < 4; ++b) {
                const int r = 16*mt + 4*quad + b;
                const float g = gv[r];
                const float cc = c2b[(size_t)r*DD + col];
                out[(row0 + r)*DD + col] = g * tanhf(acc[mt][nt][b] + bfv) + (1.f - g) * cc;
            }
        }
    }
}

extern "C" void kernel_launch(void* const* d_in, const int* in_sizes, int n_in,
                              void* d_out, int out_size, void* d_ws, size_t ws_size,
                              hipStream_t stream)
{
    const float* c1 = (const float*)d_in[0];
    const float* c2 = (const float*)d_in[1];
    const unsigned char* cmask = (const unsigned char*)d_in[2];
    const float* Wf = (const float*)d_in[3];
    const float* bf = (const float*)d_in[4];
    const float* Wg = (const float*)d_in[5];
    const float* bg = (const float*)d_in[6];

    const size_t aug_elems   = (size_t)16384 * 256;      // 4,194,304 floats
    const size_t frag_elems  = (size_t)98304;            // uints per Whi/Wlo buffer

    // 2-way layout (R2-proven): Op[2*aug] | mlp2 | aug ; Wfrag aliases Op (dead after combine).
    const size_t opart_elems = (size_t)2 * aug_elems;
    const size_t ml2_elems   = (size_t)2 * 16384 * 2;
    const size_t need2       = (opart_elems + ml2_elems + aug_elems) * sizeof(float); // 50,593,792 B

    float* wsf = (float*)d_ws;

    if (ws_size >= need2) {
        // ---- 2-way K-split, 8-wave blocks: 256 blocks x 512 thr ----
        float* Op  = wsf;
        float* mlp = wsf + opart_elems;
        float* aug = mlp + ml2_elems;
        unsigned* Whi = (unsigned*)Op;
        unsigned* Wlo = Whi + frag_elems;
        float*    gw  = (float*)(Wlo + frag_elems);

        attn_kernel<<<dim3(256), dim3(512), 0, stream>>>(c1, c2, cmask,
                                                         Op, Op + aug_elems, mlp, 1024, 1);
        combine_kernel<<<dim3(4096), dim3(256), 0, stream>>>(Op, Op + aug_elems, mlp, aug);
        prep_kernel<<<dim3(385), dim3(256), 0, stream>>>(Wf, Wg, Whi, Wlo, gw);
        fusion_mfma<<<dim3(256), dim3(512), 0, stream>>>(c2, aug, Whi, Wlo, gw, bg, bf, (float*)d_out);
    } else {
        // ---- no-split fallback: 128 blocks x 512 thr ----
        float* aug = wsf;
        float* mlp = wsf;
        unsigned* Whi = (unsigned*)(wsf + aug_elems);
        unsigned* Wlo = Whi + frag_elems;
        float*    gw  = (float*)(Wlo + frag_elems);

        attn_kernel<<<dim3(128), dim3(512), 0, stream>>>(c1, c2, cmask,
                                                         aug, aug, mlp, 2048, 0);
        prep_kernel<<<dim3(385), dim3(256), 0, stream>>>(Wf, Wg, Whi, Wlo, gw);
        fusion_mfma<<<dim3(256), dim3(512), 0, stream>>>(c2, aug, Whi, Wlo, gw, bg, bf, (float*)d_out);
    }
}

// Round 7
// 246.137 us; speedup vs baseline: 8.6782x; 1.0214x over previous
//
#include <hip/hip_runtime.h>
#include <math.h>

#define BB 8
#define LL 2048
#define DD 256

typedef float  f4_t __attribute__((ext_vector_type(4)));
typedef short  s8_t __attribute__((ext_vector_type(8)));

union S8U { s8_t v; unsigned u[4]; };

__device__ __forceinline__ unsigned bitsf(float x){ union{float f; unsigned u;} c; c.f=x; return c.u; }
__device__ __forceinline__ float fbits(unsigned u){ union{float f; unsigned u;} c; c.u=u; return c.f; }
// pack two fp32 -> two bf16 (truncate), elem0 in low half
__device__ __forceinline__ unsigned pkhi(float a, float b){ return (bitsf(a)>>16) | (bitsf(b)&0xffff0000u); }
// pack two fp32 -> two bf16 (round-nearest-ish)
__device__ __forceinline__ unsigned pkrn(float a, float b){
    unsigned ua = bitsf(a) + 0x8000u, ub = bitsf(b) + 0x8000u;
    return (ua>>16) | (ub&0xffff0000u);
}

// sigma: row e (0..31) of the key tile -> Vperm slot; makes P's MFMA C/D layout
// directly usable as the PV A-operand (slot k=8q+4a+b holds j=16a+4q+b).
__device__ __forceinline__ int vslot(int e){ return ((e>>2)&3)*8 + ((e>>4)<<2) + (e&3); }

// ---------------- MFMA flash attention — R7 (= R6 with the launch_bounds fix) ----------------
// R6 failure audit: 108,544 B static LDS + __launch_bounds__(512,2) is an
// unsatisfiable promise (2 blocks/CU would need 212 KB > 160 KB LDS) -> compile/
// launch failure. Fix: (512,1). The 512-thread block still forces 2 waves/SIMD
// residency; grid 256 = 1 block/CU, same occupancy as R5 (21%).
// Changes vs R5 (unchanged from R6):
//  (a) double-buffered K/V LDS: ONE barrier per tile; staging conversion
//      (~80 VALU) + LDS writes leave the serialized inter-barrier window.
//  (b) Vp restrided 17 -> 20 uints: PV fragments 16-B aligned ->
//      64x ds_read_b32 -> 16x ds_read_b128 per thread/tile.
//  (c) defer-max THR=0: skip O-rescale when __all(tile_max <= m_s) —
//      bitwise identical when skipped (al would be exactly 1).
__global__ __launch_bounds__(512,1)
void attn_kernel(const float* __restrict__ c1, const float* __restrict__ c2,
                 const unsigned char* __restrict__ cmask,
                 float* __restrict__ o0, float* __restrict__ o1,
                 float* __restrict__ mlp,
                 int klen, int split)
{
    __shared__ short    KhiS[2][32*264];
    __shared__ short    KloS[2][32*264];
    __shared__ unsigned VpS [2][256*20];

    const int tid  = threadIdx.x;
    const int lane = tid & 63;
    const int w    = tid >> 6;          // 0..7
    const int il   = lane & 15;
    const int quad = lane >> 4;
    const int col  = tid & 255;         // staging column (d-index)
    const int hr   = (tid >> 8) * 16;   // staging row base (0 or 16)

    const int blk  = blockIdx.x;
    const int bb   = blk & 7;
    const int qb   = (blk >> 3) & 15;
    const int half = split ? ((blk >> 7) & 1) : 0;
    const int kb   = half * klen;

    float* ob = half ? o1 : o0;

    const float* c1b = c1 + (size_t)bb * LL * DD;
    const float* c2b = c2 + (size_t)bb * LL * DD;
    const unsigned char* mb = cmask + (size_t)bb * LL;

    const int q0w = qb*128 + w*16;      // 16 q-rows per wave

    // Q fragments (hi/lo bf16 split), 1 n-tile per wave
    s8_t qh[8], ql[8];
    {
        const float* qp = c2b + (size_t)(q0w + il)*DD + quad*8;
#pragma unroll
        for (int kd = 0; kd < 8; ++kd) {
            float4 x0 = *(const float4*)(qp + kd*32);
            float4 x1 = *(const float4*)(qp + kd*32 + 4);
            float e[8] = {x0.x,x0.y,x0.z,x0.w,x1.x,x1.y,x1.z,x1.w};
            S8U h, l;
#pragma unroll
            for (int p2 = 0; p2 < 4; ++p2) {
                float a = e[2*p2], b = e[2*p2+1];
                h.u[p2] = pkhi(a, b);
                float alo = a - fbits(bitsf(a)&0xffff0000u);
                float blo = b - fbits(bitsf(b)&0xffff0000u);
                l.u[p2] = pkhi(alo, blo);
            }
            qh[kd] = h.v; ql[kd] = l.v;
        }
    }

    f4_t o[16];
#pragma unroll
    for (int n = 0; n < 16; ++n) o[n] = (f4_t)0.0f;
    float m_s = -INFINITY;
    float l_s = 0.f;

    const int NT = klen >> 5;
    float g[16];

#define STAGE_WRITE(KH, KL, VP) do { \
    _Pragma("unroll") \
    for (int e_ = 0; e_ < 16; ++e_) { \
        unsigned ub_ = bitsf(g[e_]); \
        (KH)[(hr + e_)*264 + col] = (short)(ub_ >> 16); \
        float lo_ = g[e_] - fbits(ub_ & 0xffff0000u); \
        (KL)[(hr + e_)*264 + col] = (short)(bitsf(lo_) >> 16); \
    } \
    _Pragma("unroll") \
    for (int e_ = 0; e_ < 16; e_ += 2) \
        (VP)[col*20 + (vslot(hr + e_)>>1)] = pkrn(g[e_], g[e_+1]); \
} while (0)

    // stage tile 0 into buffer 0
#pragma unroll
    for (int e = 0; e < 16; ++e) g[e] = c1b[(size_t)(kb + hr + e)*DD + col];
    STAGE_WRITE(KhiS[0], KloS[0], VpS[0]);
    __syncthreads();

    int cur = 0;
    for (int kt = 0; kt < NT; ++kt) {
        const int k0 = kt << 5;
        if (kt + 1 < NT) {
#pragma unroll
            for (int e = 0; e < 16; ++e)
                g[e] = c1b[(size_t)(kb + k0 + 32 + hr + e)*DD + col];
        }

        const short*    Khi = KhiS[cur];
        const short*    Klo = KloS[cur];
        const unsigned* Vp  = VpS[cur];

        f4_t acc[2];
        acc[0] = (f4_t)0.0f;
        acc[1] = (f4_t)0.0f;

#pragma unroll
        for (int kd = 0; kd < 8; ++kd) {
            s8_t ah0 = *(const s8_t*)&Khi[(il     )*264 + kd*32 + quad*8];
            s8_t ah1 = *(const s8_t*)&Khi[(16 + il)*264 + kd*32 + quad*8];
            s8_t al0 = *(const s8_t*)&Klo[(il     )*264 + kd*32 + quad*8];
            s8_t al1 = *(const s8_t*)&Klo[(16 + il)*264 + kd*32 + quad*8];
            acc[0] = __builtin_amdgcn_mfma_f32_16x16x32_bf16(ah0, qh[kd], acc[0], 0,0,0);
            acc[1] = __builtin_amdgcn_mfma_f32_16x16x32_bf16(ah1, qh[kd], acc[1], 0,0,0);
            acc[0] = __builtin_amdgcn_mfma_f32_16x16x32_bf16(al0, qh[kd], acc[0], 0,0,0);
            acc[1] = __builtin_amdgcn_mfma_f32_16x16x32_bf16(al1, qh[kd], acc[1], 0,0,0);
            acc[0] = __builtin_amdgcn_mfma_f32_16x16x32_bf16(ah0, ql[kd], acc[0], 0,0,0);
            acc[1] = __builtin_amdgcn_mfma_f32_16x16x32_bf16(ah1, ql[kd], acc[1], 0,0,0);
        }

        unsigned mu[2];
#pragma unroll
        for (int mj = 0; mj < 2; ++mj)
            mu[mj] = *(const unsigned*)(mb + kb + k0 + 16*mj + 4*quad);

        // online softmax (defer-max THR=0)
        const int ig = q0w + il;
        float tm = -INFINITY;           // this tile's max
        f4_t p[2];
#pragma unroll
        for (int mj = 0; mj < 2; ++mj) {
#pragma unroll
            for (int b = 0; b < 4; ++b) {
                int jg = kb + k0 + 16*mj + 4*quad + b;
                float s = acc[mj][b];
                bool dead = (((mu[mj] >> (8*b)) & 0xff) != 0) || (jg == ig);
                s = dead ? -INFINITY : s;
                p[mj][b] = s;
                tm = fmaxf(tm, s);
            }
        }
        tm = fmaxf(tm, __shfl_xor(tm, 16, 64));
        tm = fmaxf(tm, __shfl_xor(tm, 32, 64));
        const bool stable = __all(tm <= m_s);   // wave-uniform
        const float mn = stable ? m_s : fmaxf(m_s, tm);
        float rs = 0.f;
#pragma unroll
        for (int mj = 0; mj < 2; ++mj) {
#pragma unroll
            for (int b = 0; b < 4; ++b) {
                float pe = __expf(p[mj][b] - mn);
                p[mj][b] = pe;
                rs += pe;
            }
        }
        rs += __shfl_xor(rs, 16, 64);
        rs += __shfl_xor(rs, 32, 64);
        if (!stable) {
            float al = __expf(m_s - mn);
            l_s = l_s*al + rs;
            m_s = mn;
            float am[4];
#pragma unroll
            for (int b = 0; b < 4; ++b) am[b] = __shfl(al, 4*quad + b, 64);
#pragma unroll
            for (int n = 0; n < 16; ++n) {
#pragma unroll
                for (int b = 0; b < 4; ++b) o[n][b] *= am[b];
            }
        } else {
            l_s += rs;
        }

        // pack P -> bf16 A-fragment
        s8_t ap;
        {
            S8U a;
            a.u[0] = pkrn(p[0][0], p[0][1]);
            a.u[1] = pkrn(p[0][2], p[0][3]);
            a.u[2] = pkrn(p[1][0], p[1][1]);
            a.u[3] = pkrn(p[1][2], p[1][3]);
            ap = a.v;
        }
#pragma unroll
        for (int n = 0; n < 16; ++n) {
            s8_t bv = *(const s8_t*)(Vp + (16*n + il)*20 + quad*4);
            o[n] = __builtin_amdgcn_mfma_f32_16x16x32_bf16(ap, bv, o[n], 0,0,0);
        }

        // stage next tile into the other buffer (no barrier needed before:
        // buffer cur^1 was last read two iterations ago, and the barrier at
        // the END of the previous iteration already separated that use)
        if (kt + 1 < NT) {
            short*    KhiN = KhiS[cur^1];
            short*    KloN = KloS[cur^1];
            unsigned* VpN  = VpS[cur^1];
            STAGE_WRITE(KhiN, KloN, VpN);
        }
        __syncthreads();
        cur ^= 1;
    }
#undef STAGE_WRITE

    const int rbq = bb*LL + q0w;
    if (split) {
        const int rbase = rbq + 4*quad;
#pragma unroll
        for (int n = 0; n < 16; ++n) {
            const int d = 16*n + il;
#pragma unroll
            for (int b = 0; b < 4; ++b)
                ob[(size_t)(rbase + b)*DD + d] = o[n][b];
        }
        if (lane < 16) {
            int r = rbq + lane;
            *(float2*)(&mlp[((size_t)half*16384 + r)*2]) = make_float2(m_s, l_s);
        }
    } else {
        float invl[4];
#pragma unroll
        for (int b = 0; b < 4; ++b) invl[b] = 1.0f / __shfl(l_s, 4*quad + b, 64);
        const int rbase = rbq + 4*quad;
#pragma unroll
        for (int n = 0; n < 16; ++n) {
            const int d = 16*n + il;
#pragma unroll
            for (int b = 0; b < 4; ++b)
                ob[(size_t)(rbase + b)*DD + d] = o[n][b] * invl[b];
        }
    }
}

// ---------------- prep (unchanged) ----------------
__global__ __launch_bounds__(256)
void prep_kernel(const float* __restrict__ Wf, const float* __restrict__ Wg,
                 unsigned* __restrict__ Whi, unsigned* __restrict__ Wlo,
                 float* __restrict__ gw)
{
    if (blockIdx.x == 384) {
#pragma unroll
        for (int i = 0; i < 3; ++i) {
            int kl = threadIdx.x;
            float v = (i == 0) ? (Wg[kl] + Wg[768 + kl])
                    : (i == 1) ? (Wg[256 + kl] - Wg[768 + kl])
                               :  Wg[512 + kl];
            gw[i*256 + kl] = v;
        }
        return;
    }
    int t    = blockIdx.x*256 + threadIdx.x;    // [0, 98304)
    int p    = t & 3;
    int lane = (t >> 2) & 63;
    int nt   = (t >> 8) & 15;
    int g2   = t >> 12;                          // kc*3 + seg, [0,24)
    int seg  = g2 % 3;
    int kc   = g2 / 3;
    int kl   = kc*32 + (lane >> 4)*8 + 2*p;
    int n    = nt*16 + (lane & 15);
    float v0, v1;
    if (seg == 0) {
        v0 = Wf[(size_t)kl*DD + n]       + Wf[(size_t)(768 + kl)*DD + n];
        v1 = Wf[(size_t)(kl + 1)*DD + n] + Wf[(size_t)(769 + kl)*DD + n];
    } else if (seg == 1) {
        v0 = Wf[(size_t)(256 + kl)*DD + n] - Wf[(size_t)(768 + kl)*DD + n];
        v1 = Wf[(size_t)(257 + kl)*DD + n] - Wf[(size_t)(769 + kl)*DD + n];
    } else {
        v0 = Wf[(size_t)(512 + kl)*DD + n];
        v1 = Wf[(size_t)(513 + kl)*DD + n];
    }
    Whi[t] = pkhi(v0, v1);
    float l0 = v0 - fbits(bitsf(v0) & 0xffff0000u);
    float l1 = v1 - fbits(bitsf(v1) & 0xffff0000u);
    Wlo[t] = pkrn(l0, l1);
}

// ---------------- MFMA fusion — inline flash-combine (combine kernel removed) ----------------
// R5 shape (512 thr, 8 waves, 32 cols/wave) + the split-K combine folded in:
// per-thread per-mt factors ca0/ca1 (= a_h*inv) hoisted before the K loop; the
// aug value is reconstructed as x0*ca0 + x1*ca1 at staging time. Saves the
// 4096-block combine kernel (~48 MB traffic + a launch).
__global__ __launch_bounds__(512,1)
void fusion_mfma(const float* __restrict__ c2,
                 const float* __restrict__ P0, const float* __restrict__ P1,
                 const float* __restrict__ mlp,
                 const unsigned* __restrict__ Whi, const unsigned* __restrict__ Wlo,
                 const float* __restrict__ gw, const float* __restrict__ bg,
                 const float* __restrict__ bf, float* __restrict__ out, int ns)
{
    __shared__ float gwL[768];
    __shared__ float gv[64];

    const int tid  = threadIdx.x;
    const int lane = tid & 63;
    const int w    = tid >> 6;          // 0..7
    const int il   = lane & 15;
    const int quad = lane >> 4;
    const size_t row0 = (size_t)blockIdx.x * 64;

    const float* c2b = c2 + row0*DD;
    const float* P0b = P0 + row0*DD;
    const float* P1b = P1 + row0*DD;

    for (int i = tid; i < 768; i += 512) gwL[i] = gw[i];

    // per-row combine factors for this thread's 4 staging rows (16mt + il)
    float ca0[4], ca1[4];
#pragma unroll
    for (int mt = 0; mt < 4; ++mt) { ca0[mt] = 1.f; ca1[mt] = 0.f; }
    if (ns == 2) {
#pragma unroll
        for (int mt = 0; mt < 4; ++mt) {
            const size_t r = row0 + 16*mt + il;
            float m0 = mlp[r*2],             l0 = mlp[r*2 + 1];
            float m1 = mlp[(16384 + r)*2],   l1 = mlp[(16384 + r)*2 + 1];
            float M  = fmaxf(m0, m1);
            float a0 = __expf(m0 - M), a1 = __expf(m1 - M);
            float inv = 1.0f / (a0*l0 + a1*l1);
            ca0[mt] = a0*inv; ca1[mt] = a1*inv;
        }
    }
    __syncthreads();

    f4_t acc[4][2];
#pragma unroll
    for (int mt = 0; mt < 4; ++mt)
#pragma unroll
        for (int nt = 0; nt < 2; ++nt) acc[mt][nt] = (f4_t)0.0f;
    float gp[4] = {0.f, 0.f, 0.f, 0.f};

    for (int kc = 0; kc < 8; ++kc) {
        s8_t za[4], zb[4], zc[4];
        const int c0 = kc*32 + quad*8;
#pragma unroll
        for (int mt = 0; mt < 4; ++mt) {
            const float* pr = c2b + (size_t)(16*mt + il)*DD + c0;
            const float* p0 = P0b + (size_t)(16*mt + il)*DD + c0;
            float4 a0 = *(const float4*)pr, a1 = *(const float4*)(pr + 4);
            f4_t   u0 = *(const f4_t*)p0,   u1 = *(const f4_t*)(p0 + 4);
            if (ns == 2) {
                const float* p1 = P1b + (size_t)(16*mt + il)*DD + c0;
                f4_t v0 = *(const f4_t*)p1, v1 = *(const f4_t*)(p1 + 4);
                u0 = u0*ca0[mt] + v0*ca1[mt];
                u1 = u1*ca0[mt] + v1*ca1[mt];
            }
            float ea[8] = {a0.x,a0.y,a0.z,a0.w,a1.x,a1.y,a1.z,a1.w};
            float eu[8] = {u0[0],u0[1],u0[2],u0[3],u1[0],u1[1],u1[2],u1[3]};
#pragma unroll
            for (int j = 0; j < 8; ++j)
                gp[mt] += ea[j]*gwL[c0+j] + eu[j]*gwL[256+c0+j] + (ea[j]*eu[j])*gwL[512+c0+j];
            S8U A, U, Pd;
#pragma unroll
            for (int p = 0; p < 4; ++p) {
                A.u[p]  = pkrn(ea[2*p], ea[2*p+1]);
                U.u[p]  = pkrn(eu[2*p], eu[2*p+1]);
                Pd.u[p] = pkrn(ea[2*p]*eu[2*p], ea[2*p+1]*eu[2*p+1]);
            }
            za[mt] = A.v; zb[mt] = U.v; zc[mt] = Pd.v;
        }
#pragma unroll
        for (int nt = 0; nt < 2; ++nt) {
            const int ntg = w*2 + nt;     // 0..15
            const size_t f0 = ((size_t)((kc*3 + 0)*16 + ntg)*64 + lane)*4;
            const size_t f1 = ((size_t)((kc*3 + 1)*16 + ntg)*64 + lane)*4;
            const size_t f2 = ((size_t)((kc*3 + 2)*16 + ntg)*64 + lane)*4;
            s8_t w0h = *(const s8_t*)(Whi + f0), w0l = *(const s8_t*)(Wlo + f0);
            s8_t w1h = *(const s8_t*)(Whi + f1), w1l = *(const s8_t*)(Wlo + f1);
            s8_t w2h = *(const s8_t*)(Whi + f2), w2l = *(const s8_t*)(Wlo + f2);
#pragma unroll
            for (int mt = 0; mt < 4; ++mt) {
                acc[mt][nt] = __builtin_amdgcn_mfma_f32_16x16x32_bf16(za[mt], w0h, acc[mt][nt], 0,0,0);
                acc[mt][nt] = __builtin_amdgcn_mfma_f32_16x16x32_bf16(za[mt], w0l, acc[mt][nt], 0,0,0);
                acc[mt][nt] = __builtin_amdgcn_mfma_f32_16x16x32_bf16(zb[mt], w1h, acc[mt][nt], 0,0,0);
                acc[mt][nt] = __builtin_amdgcn_mfma_f32_16x16x32_bf16(zb[mt], w1l, acc[mt][nt], 0,0,0);
                acc[mt][nt] = __builtin_amdgcn_mfma_f32_16x16x32_bf16(zc[mt], w2h, acc[mt][nt], 0,0,0);
                acc[mt][nt] = __builtin_amdgcn_mfma_f32_16x16x32_bf16(zc[mt], w2l, acc[mt][nt], 0,0,0);
            }
        }
    }

    // gate reduce over the 4 quad lanes; wave 0 publishes
#pragma unroll
    for (int mt = 0; mt < 4; ++mt) {
        float gg = gp[mt];
        gg += __shfl_xor(gg, 16, 64);
        gg += __shfl_xor(gg, 32, 64);
        if (w == 0 && quad == 0) gv[16*mt + il] = gg;
    }
    __syncthreads();
    if (tid < 64) gv[tid] = 1.0f / (1.0f + __expf(-(gv[tid] + bg[0])));
    __syncthreads();

    // epilogue: row = 16mt + 4quad + b, col = 32w + 16nt + il
#pragma unroll
    for (int nt = 0; nt < 2; ++nt) {
        const int col = w*32 + nt*16 + il;
        const float bfv = bf[col];
#pragma unroll
        for (int mt = 0; mt < 4; ++mt) {
#pragma unroll
            for (int b = 0; b < 4; ++b) {
                const int r = 16*mt + 4*quad + b;
                const float g = gv[r];
                const float cc = c2b[(size_t)r*DD + col];
                out[(row0 + r)*DD + col] = g * tanhf(acc[mt][nt][b] + bfv) + (1.f - g) * cc;
            }
        }
    }
}

extern "C" void kernel_launch(void* const* d_in, const int* in_sizes, int n_in,
                              void* d_out, int out_size, void* d_ws, size_t ws_size,
                              hipStream_t stream)
{
    const float* c1 = (const float*)d_in[0];
    const float* c2 = (const float*)d_in[1];
    const unsigned char* cmask = (const unsigned char*)d_in[2];
    const float* Wf = (const float*)d_in[3];
    const float* bf = (const float*)d_in[4];
    const float* Wg = (const float*)d_in[5];
    const float* bg = (const float*)d_in[6];

    const size_t aug_elems   = (size_t)16384 * 256;      // 4,194,304 floats
    const size_t frag_elems  = (size_t)98304;            // uints per Whi/Wlo buffer

    // Layout: Op0 | Op1 | mlp2 | Wfrag(Whi,Wlo,gw).
    // Op0/Op1 stay live through fusion (inline combine), so Wfrag occupies the
    // slot formerly used by aug — no aliasing with live data.
    const size_t ml2_elems = (size_t)2 * 16384 * 2;
    const size_t need2     = (2*aug_elems + ml2_elems + aug_elems) * sizeof(float); // same 50,593,792 B gate

    float* wsf = (float*)d_ws;

    if (ws_size >= need2) {
        float* Op0 = wsf;
        float* Op1 = wsf + aug_elems;
        float* mlp = wsf + 2*aug_elems;
        unsigned* Whi = (unsigned*)(wsf + 2*aug_elems + ml2_elems);
        unsigned* Wlo = Whi + frag_elems;
        float*    gw  = (float*)(Wlo + frag_elems);

        attn_kernel<<<dim3(256), dim3(512), 0, stream>>>(c1, c2, cmask,
                                                         Op0, Op1, mlp, 1024, 1);
        prep_kernel<<<dim3(385), dim3(256), 0, stream>>>(Wf, Wg, Whi, Wlo, gw);
        fusion_mfma<<<dim3(256), dim3(512), 0, stream>>>(c2, Op0, Op1, mlp,
                                                         Whi, Wlo, gw, bg, bf,
                                                         (float*)d_out, 2);
    } else {
        // ---- no-split fallback: attn normalizes in-kernel; fusion ns==1 ----
        float* aug = wsf;
        unsigned* Whi = (unsigned*)(wsf + aug_elems);
        unsigned* Wlo = Whi + frag_elems;
        float*    gw  = (float*)(Wlo + frag_elems);

        attn_kernel<<<dim3(128), dim3(512), 0, stream>>>(c1, c2, cmask,
                                                         aug, aug, wsf, 2048, 0);
        prep_kernel<<<dim3(385), dim3(256), 0, stream>>>(Wf, Wg, Whi, Wlo, gw);
        fusion_mfma<<<dim3(256), dim3(512), 0, stream>>>(c2, aug, aug, wsf,
                                                         Whi, Wlo, gw, bg, bf,
                                                         (float*)d_out, 1);
    }
}